// Round 4
// baseline (5575.013 us; speedup 1.0000x reference)
//
#include <hip/hip_runtime.h>
#include <cstdint>
#include <cstddef>

#define T_LEN 512
#define S_LEN 512
#define HID   1024
#define AD    256
#define VOC   50257
#define G3    3072
#define NWG   256
#define NT    512
#define NPART (197*4)

typedef unsigned long long u64;

// ---------------- workspace layout (float offsets) ----------------
#define WS_GENC   0
#define WS_GITOK  (WS_GENC + G3*S_LEN)          // [512][3072]
#define WS_EX     (WS_GITOK + T_LEN*G3)         // [512][256]
#define WS_H1     (WS_EX + S_LEN*AD)            // [512][1024]
#define WS_FC1    (WS_H1 + T_LEN*HID)           // [512][32]
#define WS_ROWP   (WS_FC1 + T_LEN*32)           // [512][788]
#define WS_INV    (WS_ROWP + T_LEN*NPART)
#define WS_TAGF   (((WS_INV + T_LEN) + 3) & ~3) // 16B-aligned start of tag region

// ---- tagged-dataflow region (u64 indices, SP-strided) ----
#define SP 2                                    // 16B per word (spread pollers)
#define TG_NH0 0
#define TG_NH1 (TG_NH0 + 2*1024*SP)
#define TG_W   (TG_NH1 + 2*1024*SP)
#define TG_U0  (TG_W   + 2*512*SP)
#define TG_U1  (TG_U0  + 2*256*SP)
#define TG_E0  (TG_U1  + 2*256*SP)
#define TG_E1  (TG_E0  + 2*256*SP)
#define TG_TOT (TG_E1  + 2*256*SP)              // 14336 u64

__device__ inline float wred64(float v) {
  v += __shfl_xor(v, 32, 64); v += __shfl_xor(v, 16, 64); v += __shfl_xor(v, 8, 64);
  v += __shfl_xor(v, 4, 64);  v += __shfl_xor(v, 2, 64);  v += __shfl_xor(v, 1, 64);
  return v;
}
__device__ inline float fast_sigmoid(float x) { return 1.f / (1.f + __expf(-x)); }
__device__ inline float fast_tanh(float x) {
  float e = __expf(2.f * x);
  return 1.f - 2.f / (e + 1.f);
}

// ---- tagged 8B dataflow words: value+signal in one atomic ----
__device__ inline u64 ald(const u64* p) {
  return __hip_atomic_load(p, __ATOMIC_RELAXED, __HIP_MEMORY_SCOPE_AGENT);
}
__device__ inline void stq(u64* p, float v, unsigned tag) {
  __hip_atomic_store(p, ((u64)tag << 32) | (u64)__float_as_uint(v),
                     __ATOMIC_RELAXED, __HIP_MEMORY_SCOPE_AGENT);
}
__device__ inline float poll1(const u64* p, unsigned tag) {
  u64 x = ald(p);
  while ((unsigned)(x >> 32) != tag) { __builtin_amdgcn_s_sleep(1); x = ald(p); }
  return __uint_as_float((unsigned)x);
}
__device__ inline void poll2(const u64* p0, const u64* p1, unsigned tag, float& r0, float& r1) {
  u64 x0 = ald(p0), x1 = ald(p1);
  while (((unsigned)(x0 >> 32) != tag) | ((unsigned)(x1 >> 32) != tag)) {
    __builtin_amdgcn_s_sleep(1); x0 = ald(p0); x1 = ald(p1);
  }
  r0 = __uint_as_float((unsigned)x0); r1 = __uint_as_float((unsigned)x1);
}
__device__ inline void poll4(const u64* p0, const u64* p1, const u64* p2, const u64* p3,
                             unsigned tag, float& r0, float& r1, float& r2, float& r3) {
  u64 x0 = ald(p0), x1 = ald(p1), x2 = ald(p2), x3 = ald(p3);
  while (((unsigned)(x0 >> 32) != tag) | ((unsigned)(x1 >> 32) != tag) |
         ((unsigned)(x2 >> 32) != tag) | ((unsigned)(x3 >> 32) != tag)) {
    __builtin_amdgcn_s_sleep(1);
    x0 = ald(p0); x1 = ald(p1); x2 = ald(p2); x3 = ald(p3);
  }
  r0 = __uint_as_float((unsigned)x0); r1 = __uint_as_float((unsigned)x1);
  r2 = __uint_as_float((unsigned)x2); r3 = __uint_as_float((unsigned)x3);
}

__device__ inline float qdot4(const float4& a0, const float4& a1, const float4& a2, const float4& a3,
                              const float4& x0, const float4& x1, const float4& x2, const float4& x3) {
  float a = 0.f;
  a = fmaf(a0.x, x0.x, a); a = fmaf(a0.y, x0.y, a); a = fmaf(a0.z, x0.z, a); a = fmaf(a0.w, x0.w, a);
  a = fmaf(a1.x, x1.x, a); a = fmaf(a1.y, x1.y, a); a = fmaf(a1.z, x1.z, a); a = fmaf(a1.w, x1.w, a);
  a = fmaf(a2.x, x2.x, a); a = fmaf(a2.y, x2.y, a); a = fmaf(a2.z, x2.z, a); a = fmaf(a2.w, x2.w, a);
  a = fmaf(a3.x, x3.x, a); a = fmaf(a3.y, x3.y, a); a = fmaf(a3.z, x3.z, a); a = fmaf(a3.w, x3.w, a);
  return a;
}
__device__ inline float qdot2(const float4& a0, const float4& a1,
                              const float4& x0, const float4& x1) {
  float a = 0.f;
  a = fmaf(a0.x, x0.x, a); a = fmaf(a0.y, x0.y, a); a = fmaf(a0.z, x0.z, a); a = fmaf(a0.w, x0.w, a);
  a = fmaf(a1.x, x1.x, a); a = fmaf(a1.y, x1.y, a); a = fmaf(a1.z, x1.z, a); a = fmaf(a1.w, x1.w, a);
  return a;
}

// ---------------- init: zero all tag words (tag 0 == initial zero state) ----------------
__global__ void k_init(float* ws) {
  u64* TG = (u64*)(ws + WS_TAGF);
  const int i = blockIdx.x * 256 + threadIdx.x;
  if (i < TG_TOT) TG[i] = 0ull;
}

// ---------------- generic tiled fp32 GEMM (pre/post passes) ----------------
__global__ __launch_bounds__(256) void k_gemm(
    const float* __restrict__ A, int lda, const int* __restrict__ gidx,
    const float* __restrict__ B, int ldb, int kofs,
    const float* __restrict__ bias, float* __restrict__ C, int ldc,
    int M, int N, int act)
{
  __shared__ float As[64][33];
  __shared__ float Bs[64][33];
  const int bm = blockIdx.y * 64, bn = blockIdx.x * 64;
  const int tx = threadIdx.x & 15, ty = threadIdx.x >> 4;
  float acc[4][4] = {};
  const int lin = threadIdx.x * 8;
  const int lr = lin >> 5;
  const int lc = lin & 31;
  for (int k0 = 0; k0 < 1024; k0 += 32) {
    {
      const int gm = bm + lr;
      float4 v0 = {0,0,0,0}, v1 = {0,0,0,0};
      if (gm < M) {
        const int row = gidx ? gidx[gm] : gm;
        const float* p = A + (size_t)row * lda + k0 + lc;
        v0 = *(const float4*)p; v1 = *(const float4*)(p + 4);
      }
      As[lr][lc+0]=v0.x; As[lr][lc+1]=v0.y; As[lr][lc+2]=v0.z; As[lr][lc+3]=v0.w;
      As[lr][lc+4]=v1.x; As[lr][lc+5]=v1.y; As[lr][lc+6]=v1.z; As[lr][lc+7]=v1.w;
    }
    {
      const int gn = bn + lr;
      float4 v0 = {0,0,0,0}, v1 = {0,0,0,0};
      if (gn < N) {
        const float* p = B + (size_t)gn * ldb + kofs + k0 + lc;
        v0 = *(const float4*)p; v1 = *(const float4*)(p + 4);
      }
      Bs[lr][lc+0]=v0.x; Bs[lr][lc+1]=v0.y; Bs[lr][lc+2]=v0.z; Bs[lr][lc+3]=v0.w;
      Bs[lr][lc+4]=v1.x; Bs[lr][lc+5]=v1.y; Bs[lr][lc+6]=v1.z; Bs[lr][lc+7]=v1.w;
    }
    __syncthreads();
    #pragma unroll
    for (int kk = 0; kk < 32; ++kk) {
      float a0 = As[ty*4+0][kk], a1 = As[ty*4+1][kk], a2 = As[ty*4+2][kk], a3 = As[ty*4+3][kk];
      float b0 = Bs[tx*4+0][kk], b1 = Bs[tx*4+1][kk], b2 = Bs[tx*4+2][kk], b3 = Bs[tx*4+3][kk];
      acc[0][0]=fmaf(a0,b0,acc[0][0]); acc[0][1]=fmaf(a0,b1,acc[0][1]); acc[0][2]=fmaf(a0,b2,acc[0][2]); acc[0][3]=fmaf(a0,b3,acc[0][3]);
      acc[1][0]=fmaf(a1,b0,acc[1][0]); acc[1][1]=fmaf(a1,b1,acc[1][1]); acc[1][2]=fmaf(a1,b2,acc[1][2]); acc[1][3]=fmaf(a1,b3,acc[1][3]);
      acc[2][0]=fmaf(a2,b0,acc[2][0]); acc[2][1]=fmaf(a2,b1,acc[2][1]); acc[2][2]=fmaf(a2,b2,acc[2][2]); acc[2][3]=fmaf(a2,b3,acc[2][3]);
      acc[3][0]=fmaf(a3,b0,acc[3][0]); acc[3][1]=fmaf(a3,b1,acc[3][1]); acc[3][2]=fmaf(a3,b2,acc[3][2]); acc[3][3]=fmaf(a3,b3,acc[3][3]);
    }
    __syncthreads();
  }
  #pragma unroll
  for (int i = 0; i < 4; ++i)
    #pragma unroll
    for (int j = 0; j < 4; ++j) {
      const int m = bm + ty*4 + i, n = bn + tx*4 + j;
      if (m < M && n < N) {
        float v = acc[i][j] + (bias ? bias[n] : 0.f);
        if (act == 1) v = fmaxf(v, 0.f);
        C[(size_t)m * ldc + n] = v;
      }
    }
}

// ---------------- persistent recurrence: 256 WGs x 512 thr, zero barriers ----------------
// All cross-WG state flows through tagged 8B words (value|tag), parity double-buffered.
// WG wg owns j-columns [4wg,4wg+4) -> 12 gate-rows of Whh0/Wih1/Whh1/Genc (reg-resident).
// waves 0..5: 2 gate-rows each. wave 6: Wh row wg (e-scores) + attn-w row 2wg.
// wave 7: Wac row wg (u) + attn-w row 2wg+1.
__global__ __launch_bounds__(NT) void k_recur(
    float* __restrict__ ws,
    const float* __restrict__ Whh0, const float* __restrict__ bhh0,
    const float* __restrict__ Wih1, const float* __restrict__ bih1,
    const float* __restrict__ Whh1, const float* __restrict__ bhh1,
    const float* __restrict__ Wh,   const float* __restrict__ bh,
    const float* __restrict__ vh,   const float* __restrict__ vhb,
    const float* __restrict__ va,   const float* __restrict__ vab,
    const float* __restrict__ Wac)
{
  const float* Genc  = ws + WS_GENC;
  const float* gitok = ws + WS_GITOK;
  const float* Ex    = ws + WS_EX;
  float* H1 = ws + WS_H1;
  u64* TG   = (u64*)(ws + WS_TAGF);
  u64* tNH0 = TG + TG_NH0;
  u64* tNH1 = TG + TG_NH1;
  u64* tW   = TG + TG_W;
  u64* tU0  = TG + TG_U0;
  u64* tU1  = TG + TG_U1;
  u64* tE0  = TG + TG_E0;
  u64* tE1  = TG + TG_E1;

  const int wg = blockIdx.x, tid = threadIdx.x;
  const int lane = tid & 63, wv = tid >> 6;

  __shared__ float xv[HID];      // staged state vector (h0n / nh0 / nh1)
  __shared__ float wl[S_LEN];    // staged attention weights
  __shared__ float cb[AD];       // c = Wa_c @ h0n
  __shared__ float sgh0[12], gh1l[12], sb0[12], sbh1[12], sacc[12];
  __shared__ float sred[8];

  // ---- persistent register-resident weights ----
  float4 wreg[28];
  if (wv < 6) {
    #pragma unroll
    for (int r = 0; r < 2; ++r) {
      const int lr = 2 * wv + r;
      const int g = (lr >> 2) * HID + wg * 4 + (lr & 3);
      const float4* p0 = (const float4*)(Whh0 + (size_t)g * HID);
      const float4* p1 = (const float4*)(Wih1 + (size_t)g * HID);
      const float4* p2 = (const float4*)(Whh1 + (size_t)g * HID);
      const float4* pg = (const float4*)(Genc + (size_t)g * S_LEN);
      #pragma unroll
      for (int p = 0; p < 4; ++p) {
        wreg[r*4+p]      = p0[p*64 + lane];
        wreg[8 + r*4+p]  = p1[p*64 + lane];
        wreg[16 + r*4+p] = p2[p*64 + lane];
      }
      #pragma unroll
      for (int p = 0; p < 2; ++p) wreg[24 + r*2+p] = pg[p*64 + lane];
    }
  } else {
    const float* Wrow = (wv == 6) ? (Wh + (size_t)wg * HID) : (Wac + (size_t)wg * HID);
    const float4* p0 = (const float4*)Wrow;
    #pragma unroll
    for (int p = 0; p < 4; ++p) wreg[p] = p0[p*64 + lane];
    const int s = 2 * wg + (wv - 6);
    wreg[4] = ((const float4*)(Ex + (size_t)s * AD))[lane];
    wreg[5] = ((const float4*)va)[lane];
  }

  float i1r = 0.f, i1z = 0.f, i1n = 0.f;
  if (tid < 4) {
    const int j = wg * 4 + tid;
    i1r = bih1[j]; i1z = bih1[HID + j]; i1n = bih1[2 * HID + j];
  }
  if (tid < 12) {
    const int g = (tid >> 2) * HID + wg * 4 + (tid & 3);
    sb0[tid] = bhh0[g];
    const float bb = bhh1[g];
    sbh1[tid] = bb;
    gh1l[tid] = bb;          // gh1(t=0) = Whh1@0 + bhh1
  }
  const float vhW = vh[wg], bhW = bh[wg];
  const float vabv = vab[0], vhb0 = vhb[0];
  __syncthreads();

  const float4* XV4 = (const float4*)xv;
  const float4* WL4 = (const float4*)wl;
  const float4* CB4 = (const float4*)cb;

  #pragma unroll 1
  for (int t = 0; t < T_LEN; ++t) {
    const int c = t & 1, pc = c ^ 1;
    const unsigned tg = (unsigned)(t + 1);  // tag written this step
    const unsigned tp = (unsigned)t;        // tag of prev-step values

    // ========== S1: alpha; h0n; c; gh0 (LDS); attention w ==========
    {
      float a0, a1, b0, b1;
      poll4(tNH0 + (size_t)(pc*1024 + tid)*SP, tNH0 + (size_t)(pc*1024 + 512 + tid)*SP,
            tNH1 + (size_t)(pc*1024 + tid)*SP, tNH1 + (size_t)(pc*1024 + 512 + tid)*SP,
            tp, a0, a1, b0, b1);
      float ep, uu0 = 0.f, uu1 = 0.f;
      if (tid < 256) {
        ep = poll1(tE0 + (size_t)(pc*256 + tid)*SP, tp);
        poll2(tU0 + (size_t)(pc*256 + tid)*SP, tU1 + (size_t)(pc*256 + tid)*SP, tp, uu0, uu1);
      } else {
        ep = poll1(tE1 + (size_t)(pc*256 + tid - 256)*SP, tp);
      }
      ep = wred64(ep);
      if (lane == 0) sred[wv] = ep;
      __syncthreads();
      const float e0s = sred[0] + sred[1] + sred[2] + sred[3] + vhb0;
      const float e1s = sred[4] + sred[5] + sred[6] + sred[7] + vhb0;
      const float ea = __expf(e0s), eb = __expf(e1s);
      const float rs = 1.f / (ea + eb);
      const float al0 = ea * rs, al1 = eb * rs;
      xv[tid]       = al0 * a0 + al1 * b0;
      xv[tid + 512] = al0 * a1 + al1 * b1;
      if (tid < 256) cb[tid] = al0 * uu0 + al1 * uu1;
      __syncthreads();
    }
    float h0j = 0.f;
    if (tid < 4) h0j = xv[wg * 4 + tid];   // captured before any later xv overwrite
    if (wv < 6) {
      const float4 x0 = XV4[lane], x1 = XV4[64+lane], x2 = XV4[128+lane], x3 = XV4[192+lane];
      float accA = qdot4(wreg[0], wreg[1], wreg[2], wreg[3], x0, x1, x2, x3);
      float accB = qdot4(wreg[4], wreg[5], wreg[6], wreg[7], x0, x1, x2, x3);
      accA = wred64(accA); accB = wred64(accB);
      if (lane == 0) {
        sgh0[2*wv]     = accA + sb0[2*wv];
        sgh0[2*wv + 1] = accB + sb0[2*wv + 1];
      }
    } else {
      const float4 e4 = wreg[4], v4 = wreg[5], c4 = CB4[lane];
      float acc = v4.x * fast_tanh(e4.x + c4.x) + v4.y * fast_tanh(e4.y + c4.y)
                + v4.z * fast_tanh(e4.z + c4.z) + v4.w * fast_tanh(e4.w + c4.w);
      acc = wred64(acc);
      if (lane == 0)
        stq(tW + (size_t)(c*512 + 2*wg + (wv - 6))*SP, __expf(acc + vabv), tg);
    }

    // ========== S2: nh0 = GRU0((Genc@w)/sum + gi_tok, gh0, h0n) ==========
    {
      float g0 = 0.f, g1 = 0.f, g2 = 0.f;
      if (tid < 4) {   // plain cached loads, issued before the poll
        const float* gp = gitok + (size_t)t * G3 + wg * 4 + tid;
        g0 = gp[0]; g1 = gp[HID]; g2 = gp[2 * HID];
      }
      const float wval = poll1(tW + (size_t)(c*512 + tid)*SP, tg);
      wl[tid] = wval;
      __syncthreads();                 // wl + sgh0 ready
      float inv = 0.f;
      if (wv == 0) {                   // wave 0 computes 1/sum(w) redundantly
        float s = 0.f;
        #pragma unroll
        for (int k = 0; k < 8; ++k) s += wl[lane + 64*k];
        s = wred64(s);
        inv = 1.f / s;
      }
      if (wv < 6) {
        const float4 w0 = WL4[lane], w1 = WL4[64 + lane];
        float accA = qdot2(wreg[24], wreg[25], w0, w1);
        float accB = qdot2(wreg[26], wreg[27], w0, w1);
        accA = wred64(accA); accB = wred64(accB);
        if (lane == 0) { sacc[2*wv] = accA; sacc[2*wv + 1] = accB; }
      }
      __syncthreads();
      if (tid < 4) {
        const float d0 = sacc[tid]     * inv + g0;
        const float d1 = sacc[4 + tid] * inv + g1;
        const float d2 = sacc[8 + tid] * inv + g2;
        const float rg = fast_sigmoid(d0 + sgh0[tid]);
        const float zg = fast_sigmoid(d1 + sgh0[4 + tid]);
        const float ng = fast_tanh(d2 + rg * sgh0[8 + tid]);
        stq(tNH0 + (size_t)(c*1024 + wg*4 + tid)*SP, (1.f - zg) * ng + zg * h0j, tg);
      }
    }

    // ========== S3: nh1 = GRU1(Wih1@nh0, gh1_prev, nh1_prev); e0, u0 ==========
    {
      float oldn = 0.f;
      if (tid < 4) oldn = poll1(tNH1 + (size_t)(pc*1024 + wg*4 + tid)*SP, tp);  // ready long ago
      float x0, x1;
      poll2(tNH0 + (size_t)(c*1024 + tid)*SP, tNH0 + (size_t)(c*1024 + 512 + tid)*SP, tg, x0, x1);
      xv[tid] = x0; xv[tid + 512] = x1;
      __syncthreads();
      const float4 y0 = XV4[lane], y1 = XV4[64+lane], y2 = XV4[128+lane], y3 = XV4[192+lane];
      if (wv < 6) {
        float accA = qdot4(wreg[8],  wreg[9],  wreg[10], wreg[11], y0, y1, y2, y3);
        float accB = qdot4(wreg[12], wreg[13], wreg[14], wreg[15], y0, y1, y2, y3);
        accA = wred64(accA); accB = wred64(accB);
        if (lane == 0) { sacc[2*wv] = accA; sacc[2*wv + 1] = accB; }
      } else {
        float acc = qdot4(wreg[0], wreg[1], wreg[2], wreg[3], y0, y1, y2, y3);
        acc = wred64(acc);
        if (lane == 0) {
          if (wv == 6) stq(tE0 + (size_t)(c*256 + wg)*SP, vhW * fast_tanh(acc + bhW), tg);
          else         stq(tU0 + (size_t)(c*256 + wg)*SP, acc, tg);
        }
      }
      __syncthreads();
      if (tid < 4) {
        const float gr = sacc[tid]     + i1r;
        const float gz = sacc[4 + tid] + i1z;
        const float gn = sacc[8 + tid] + i1n;
        const float rg = fast_sigmoid(gr + gh1l[tid]);
        const float zg = fast_sigmoid(gz + gh1l[4 + tid]);
        const float ng = fast_tanh(gn + rg * gh1l[8 + tid]);
        const float nv = (1.f - zg) * ng + zg * oldn;
        stq(tNH1 + (size_t)(c*1024 + wg*4 + tid)*SP, nv, tg);
        H1[(size_t)t * HID + wg * 4 + tid] = nv;
      }
    }

    // ========== S4: gh1_next (LDS); e1, u1 ==========
    {
      float x0, x1;
      poll2(tNH1 + (size_t)(c*1024 + tid)*SP, tNH1 + (size_t)(c*1024 + 512 + tid)*SP, tg, x0, x1);
      xv[tid] = x0; xv[tid + 512] = x1;
      __syncthreads();
      const float4 y0 = XV4[lane], y1 = XV4[64+lane], y2 = XV4[128+lane], y3 = XV4[192+lane];
      if (wv < 6) {
        float accA = qdot4(wreg[16], wreg[17], wreg[18], wreg[19], y0, y1, y2, y3);
        float accB = qdot4(wreg[20], wreg[21], wreg[22], wreg[23], y0, y1, y2, y3);
        accA = wred64(accA); accB = wred64(accB);
        if (lane == 0) {
          gh1l[2*wv]     = accA + sbh1[2*wv];
          gh1l[2*wv + 1] = accB + sbh1[2*wv + 1];
        }
      } else {
        float acc = qdot4(wreg[0], wreg[1], wreg[2], wreg[3], y0, y1, y2, y3);
        acc = wred64(acc);
        if (lane == 0) {
          if (wv == 6) stq(tE1 + (size_t)(c*256 + wg)*SP, vhW * fast_tanh(acc + bhW), tg);
          else         stq(tU1 + (size_t)(c*256 + wg)*SP, acc, tg);
        }
      }
    }
  }
}

// ---------------- output head: logits -> exp -> per-wave row partials ----------------
__global__ __launch_bounds__(256) void k_head(
    const float* __restrict__ FC1, const float* __restrict__ Wf2,
    const float* __restrict__ bf2, float* __restrict__ out, float* __restrict__ rowp)
{
  __shared__ float fcb[256 * 32];
  const int v = blockIdx.x * 256 + threadIdx.x;
  const bool ok = v < VOC;
  float wf[32];
  float bb = 0.f;
  if (ok) {
    const float4* W4 = (const float4*)(Wf2 + (size_t)v * 32);
    #pragma unroll
    for (int q = 0; q < 8; ++q) ((float4*)wf)[q] = W4[q];
    bb = bf2[v];
  }
  const int wv = threadIdx.x >> 6;
  #pragma unroll 1
  for (int half = 0; half < 2; ++half) {
    __syncthreads();
    for (int i = threadIdx.x; i < 256 * 32 / 4; i += 256)
      ((float4*)fcb)[i] = ((const float4*)(FC1 + half * 256 * 32))[i];
    __syncthreads();
    #pragma unroll 1
    for (int tt = 0; tt < 256; ++tt) {
      const int t = half * 256 + tt;
      const float4* f4 = (const float4*)(fcb + tt * 32);
      float acc = bb;
      #pragma unroll
      for (int q = 0; q < 8; ++q) {
        float4 f = f4[q];
        acc = fmaf(wf[4*q+0], f.x, acc);
        acc = fmaf(wf[4*q+1], f.y, acc);
        acc = fmaf(wf[4*q+2], f.z, acc);
        acc = fmaf(wf[4*q+3], f.w, acc);
      }
      const float w = ok ? __expf(acc) : 0.f;
      if (ok) out[(size_t)t * VOC + v] = w;
      float r = wred64(w);
      if ((threadIdx.x & 63) == 0)
        rowp[(size_t)t * NPART + (size_t)blockIdx.x * 4 + wv] = r;
    }
  }
}

__global__ __launch_bounds__(256) void k_rowsum(const float* __restrict__ rowp, float* __restrict__ inv) {
  const int t = blockIdx.x;
  float acc = 0.f;
  for (int i = threadIdx.x; i < NPART; i += 256) acc += rowp[(size_t)t * NPART + i];
  acc = wred64(acc);
  __shared__ float sr[4];
  if ((threadIdx.x & 63) == 0) sr[threadIdx.x >> 6] = acc;
  __syncthreads();
  if (threadIdx.x == 0) inv[t] = 1.f / (sr[0] + sr[1] + sr[2] + sr[3]);
}

__global__ __launch_bounds__(256) void k_scale(float* __restrict__ out, const float* __restrict__ inv) {
  const int t = blockIdx.y;
  const float s = inv[t];
  const size_t base = (size_t)t * VOC;
  const int v0 = blockIdx.x * 2048 + threadIdx.x;
  #pragma unroll
  for (int k = 0; k < 8; ++k) {
    const int v = v0 + k * 256;
    if (v < VOC) out[base + v] *= s;
  }
}

extern "C" void kernel_launch(void* const* d_in, const int* in_sizes, int n_in,
                              void* d_out, int out_size, void* d_ws, size_t ws_size,
                              hipStream_t stream) {
  const int*   dec  = (const int*)  d_in[0];
  const float* enc  = (const float*)d_in[1];
  const float* emb  = (const float*)d_in[2];
  const float* Wax  = (const float*)d_in[3];
  const float* Wac  = (const float*)d_in[4];
  const float* ba   = (const float*)d_in[5];
  const float* va   = (const float*)d_in[6];
  const float* vab  = (const float*)d_in[7];
  const float* Wih0 = (const float*)d_in[8];
  const float* bih0 = (const float*)d_in[9];
  const float* Whh0 = (const float*)d_in[10];
  const float* bhh0 = (const float*)d_in[11];
  const float* Wih1 = (const float*)d_in[12];
  const float* bih1 = (const float*)d_in[13];
  const float* Whh1 = (const float*)d_in[14];
  const float* bhh1 = (const float*)d_in[15];
  const float* Wh   = (const float*)d_in[16];
  const float* bh   = (const float*)d_in[17];
  const float* vh   = (const float*)d_in[18];
  const float* vhb  = (const float*)d_in[19];
  const float* Wf1  = (const float*)d_in[20];
  const float* bf1  = (const float*)d_in[21];
  const float* Wf2  = (const float*)d_in[22];
  const float* bf2  = (const float*)d_in[23];
  float* out = (float*)d_out;
  float* ws  = (float*)d_ws;

  k_init<<<56, 256, 0, stream>>>(ws);   // 56*256 == TG_TOT

  // Genc[r][s] = Wih0[r, :1024] . enc[s]          (M=3072, N=512)
  k_gemm<<<dim3(8, 48), 256, 0, stream>>>(Wih0, 2048, nullptr, enc, 1024, 0,
                                          nullptr, ws + WS_GENC, 512, G3, S_LEN, 0);
  // gi_tok[t][r] = emb[dec[t]] . Wih0[r, 1024:] + bih0[r]   (M=512, N=3072)
  k_gemm<<<dim3(48, 8), 256, 0, stream>>>(emb, 1024, dec, Wih0, 2048, 1024,
                                          bih0, ws + WS_GITOK, G3, T_LEN, G3, 0);
  // Ex[s][i] = enc[s] . Wa_x[i] + ba[i]           (M=512, N=256)
  k_gemm<<<dim3(4, 8), 256, 0, stream>>>(enc, 1024, nullptr, Wax, 1024, 0,
                                         ba, ws + WS_EX, AD, S_LEN, AD, 0);

  k_recur<<<NWG, NT, 0, stream>>>(ws, Whh0, bhh0, Wih1, bih1, Whh1, bhh1,
                                  Wh, bh, vh, vhb, va, vab, Wac);

  // FC1[t] = relu(Wf1 @ H1[t] + bf1)              (M=512, N=32)
  k_gemm<<<dim3(1, 8), 256, 0, stream>>>(ws + WS_H1, 1024, nullptr, Wf1, 1024, 0,
                                         bf1, ws + WS_FC1, 32, T_LEN, 32, 1);

  k_head<<<197, 256, 0, stream>>>(ws + WS_FC1, Wf2, bf2, out, ws + WS_ROWP);
  k_rowsum<<<512, 256, 0, stream>>>(ws + WS_ROWP, ws + WS_INV);
  k_scale<<<dim3(25, 512), 256, 0, stream>>>(out, ws + WS_INV);
}